// Round 3
// baseline (1507.285 us; speedup 1.0000x reference)
//
#include <hip/hip_runtime.h>
#include <hip/hip_fp16.h>

// Sinkhorn OT: n=m=4096, d=32, reg=0.1, 100 iterations, uniform marginals.
// R3: iteration passes stream ONLY K (fp16, 32MB/pass) from global. The
// scaling vector w is produced in both fp32 (for epilogue) and fp16; each
// rowpass block stages the 8KB fp16 w into LDS once, then the dot loop is
// 1 global uint4 + 1 ds_read_b128 + 4 v_dot2_f32_f16 per 16B of K.

#define NN 4096
#define MM 4096
#define DD 32
#define N_ITERS 100

static constexpr float INV_REG = 10.0f;
static constexpr float A_MARG  = 1.0f / 4096.0f;
static constexpr float B_MARG  = 1.0f / 4096.0f;

typedef _Float16 h2_t __attribute__((ext_vector_type(2)));

static __device__ __forceinline__ float dot2(unsigned a, unsigned b, float acc) {
#if __has_builtin(__builtin_amdgcn_fdot2)
    return __builtin_amdgcn_fdot2(__builtin_bit_cast(h2_t, a),
                                  __builtin_bit_cast(h2_t, b), acc, false);
#else
    float2 fa = __half22float2(*(const __half2*)&a);
    float2 fb = __half22float2(*(const __half2*)&b);
    acc = fmaf(fa.x, fb.x, acc);
    return fmaf(fa.y, fb.y, acc);
#endif
}

// ---------------------------------------------------------------------------
// Kh[i][j] = (half)exp(-||p_i - q_j||^2 / reg), row-major [4096][4096].
// Called twice: (x,y)->Kh and (y,x)->KTh. prime!=0 also primes v0 = 1/4096
// in both fp32 and fp16 ping buffers.
// grid: (4096/256, 4096/16), block 256
// ---------------------------------------------------------------------------
__global__ void compute_K_half(const float* __restrict__ p, const float* __restrict__ q,
                               __half* __restrict__ Kh, float* __restrict__ w32_prime,
                               __half* __restrict__ w16_prime, int prime) {
    const int tid = threadIdx.x;
    const int j   = blockIdx.x * 256 + tid;
    const int r0  = blockIdx.y * 16;

    if (prime && blockIdx.y == 0) {
        w32_prime[j] = B_MARG;
        w16_prime[j] = __float2half(B_MARG);
    }

    float qv[DD];
    const float4* q4 = (const float4*)(q + (size_t)j * DD);
#pragma unroll
    for (int k = 0; k < DD / 4; ++k) {
        float4 t = q4[k];
        qv[4 * k + 0] = t.x; qv[4 * k + 1] = t.y;
        qv[4 * k + 2] = t.z; qv[4 * k + 3] = t.w;
    }

    __shared__ float ps[16 * DD];
    ps[tid]       = p[(size_t)r0 * DD + tid];
    ps[tid + 256] = p[(size_t)r0 * DD + tid + 256];
    __syncthreads();

#pragma unroll 4
    for (int ii = 0; ii < 16; ++ii) {
        float acc = 0.0f;
#pragma unroll
        for (int k = 0; k < DD; ++k) {
            float d = ps[ii * DD + k] - qv[k];
            acc = fmaf(d, d, acc);
        }
        Kh[(size_t)(r0 + ii) * MM + j] = __float2half(__expf(-acc * INV_REG));
    }
}

// ---------------------------------------------------------------------------
// w_out[i] = marg / sum_j Mat[i][j] * w16_in[j]; written fp32 and fp16.
// 512 blocks x 512 threads; 8 waves/block, one row per wave. w16_in (8KB)
// staged to LDS once per block; dot loop reads only K from global.
// ---------------------------------------------------------------------------
__global__ void __launch_bounds__(512)
rowpass(const __half* __restrict__ Mat, const __half* __restrict__ w16_in,
        float marg, float* __restrict__ w32_out, __half* __restrict__ w16_out) {
    __shared__ __align__(16) __half vlds[MM];
    const int tid = threadIdx.x;

    // stage 8KB of fp16 w: 512 threads x 16B, conflict-free b128 writes
    ((uint4*)vlds)[tid] = ((const uint4*)w16_in)[tid];
    __syncthreads();

    const int lane = tid & 63;
    const int i    = blockIdx.x * 8 + (tid >> 6);
    const uint4* Mrow = (const uint4*)(Mat + (size_t)i * MM);  // 512 uint4/row
    const uint4* V    = (const uint4*)vlds;                    // 512 uint4

    float acc = 0.0f;
#pragma unroll
    for (int c = 0; c < 8; ++c) {
        const int g = c * 64 + lane;
        uint4 kk = Mrow[g];
        uint4 vv = V[g];
        acc = dot2(kk.x, vv.x, acc);
        acc = dot2(kk.y, vv.y, acc);
        acc = dot2(kk.z, vv.z, acc);
        acc = dot2(kk.w, vv.w, acc);
    }
#pragma unroll
    for (int off = 32; off > 0; off >>= 1) acc += __shfl_down(acc, off, 64);
    if (lane == 0) {
        float r = marg / acc;
        w32_out[i] = r;
        w16_out[i] = __float2half(r);
    }
}

// ---------------------------------------------------------------------------
// gamma[i][j] = u[i] * exp(-||x_i-y_j||^2/reg) * v[j]   (exact fp32 K)
// grid: (16, 256), block 256
// ---------------------------------------------------------------------------
__global__ void epilogue(const float* __restrict__ x, const float* __restrict__ y,
                         const float* __restrict__ u, const float* __restrict__ v,
                         float* __restrict__ out) {
    const int tid = threadIdx.x;
    const int j   = blockIdx.x * 256 + tid;
    const int r0  = blockIdx.y * 16;

    float yv[DD];
    const float4* y4 = (const float4*)(y + (size_t)j * DD);
#pragma unroll
    for (int k = 0; k < DD / 4; ++k) {
        float4 t = y4[k];
        yv[4 * k + 0] = t.x; yv[4 * k + 1] = t.y;
        yv[4 * k + 2] = t.z; yv[4 * k + 3] = t.w;
    }

    __shared__ float xs[16 * DD];
    __shared__ float u_lds[16];
    xs[tid]       = x[(size_t)r0 * DD + tid];
    xs[tid + 256] = x[(size_t)r0 * DD + tid + 256];
    if (tid < 16) u_lds[tid] = u[r0 + tid];
    __syncthreads();

    const float vj = v[j];
#pragma unroll 4
    for (int ii = 0; ii < 16; ++ii) {
        float acc = 0.0f;
#pragma unroll
        for (int k = 0; k < DD; ++k) {
            float d = xs[ii * DD + k] - yv[k];
            acc = fmaf(d, d, acc);
        }
        out[(size_t)(r0 + ii) * MM + j] = u_lds[ii] * __expf(-acc * INV_REG) * vj;
    }
}

extern "C" void kernel_launch(void* const* d_in, const int* in_sizes, int n_in,
                              void* d_out, int out_size, void* d_ws, size_t ws_size,
                              hipStream_t stream) {
    const float* x = (const float*)d_in[0];
    const float* y = (const float*)d_in[1];
    __half* Kh   = (__half*)d_ws;                      // 32 MB
    __half* KTh  = Kh + (size_t)NN * MM;               // 32 MB
    float*  w32u = (float*)(KTh + (size_t)NN * MM);    // 16 KB
    float*  w32v = w32u + NN;                          // 16 KB
    __half* w16u = (__half*)(w32v + MM);               // 8 KB
    __half* w16v = w16u + NN;                          // 8 KB
    float*  out  = (float*)d_out;

    compute_K_half<<<dim3(MM / 256, NN / 16), 256, 0, stream>>>(x, y, Kh, w32v, w16v, 1);
    compute_K_half<<<dim3(NN / 256, MM / 16), 256, 0, stream>>>(y, x, KTh, w32v, w16v, 0);

    for (int t = 0; t < N_ITERS; ++t) {
        rowpass<<<NN / 8, 512, 0, stream>>>(Kh,  w16v, A_MARG, w32u, w16u);  // u
        rowpass<<<MM / 8, 512, 0, stream>>>(KTh, w16u, B_MARG, w32v, w16v);  // v
    }

    epilogue<<<dim3(MM / 256, NN / 16), 256, 0, stream>>>(x, y, w32u, w32v, out);
}